// Round 14
// baseline (273.099 us; speedup 1.0000x reference)
//
#include <hip/hip_runtime.h>
#include <math.h>

#define B_ 4
#define T_ 2048
#define E_ 1024
#define H_ 16
#define D_ 64
#define CHUNK_ 128
#define NC_ 16
#define BH_ (B_ * H_)   // 64
#define M_ (B_ * T_)    // 8192

typedef __attribute__((ext_vector_type(8))) short bf16x8;
typedef __attribute__((ext_vector_type(4))) float f32x4;

__device__ __forceinline__ ushort rnbf(float f) {
  unsigned u = __float_as_uint(f);
  unsigned r = (u + 0x7FFFu + ((u >> 16) & 1u)) >> 16;
  return (ushort)r;
}

__device__ __forceinline__ float bf2f(short s) {
  return __uint_as_float(((unsigned)(ushort)s) << 16);
}

__device__ __forceinline__ void gload_lds16(const void* g, void* l) {
  __builtin_amdgcn_global_load_lds(
      (const __attribute__((address_space(1))) unsigned int*)g,
      (__attribute__((address_space(3))) unsigned int*)l, 16, 0, 0);
}

#define VMW(N) do { asm volatile("s_waitcnt vmcnt(" #N ")" ::: "memory"); \
                    __builtin_amdgcn_sched_barrier(0); } while (0)
#define BARR() do { __builtin_amdgcn_s_barrier(); \
                    __builtin_amdgcn_sched_barrier(0); } while (0)
#define LGK0() do { asm volatile("s_waitcnt lgkmcnt(0)" ::: "memory"); \
                    __builtin_amdgcn_sched_barrier(0); } while (0)

// ---------------------------------------------------------------------------
// fused fp32 -> bf16 conversion for x, w_attn, w_proj (one launch)
// ---------------------------------------------------------------------------
#define N4X_ (M_ * E_ / 4)           // 2097152
#define N4A_ (3 * E_ * E_ / 4)       // 786432
#define N4P_ (E_ * E_ / 4)           // 262144
__global__ __launch_bounds__(256) void k_cvt3(
    const float* __restrict__ x, const float* __restrict__ wa,
    const float* __restrict__ wp, ushort* __restrict__ xb,
    ushort* __restrict__ wab, ushort* __restrict__ wpb) {
  int i = blockIdx.x * 256 + threadIdx.x;
  const float* src;
  ushort* dst;
  int off;
  if (i < N4X_) { src = x; dst = xb; off = i; }
  else if (i < N4X_ + N4A_) { src = wa; dst = wab; off = i - N4X_; }
  else { src = wp; dst = wpb; off = i - (N4X_ + N4A_); }
  float4 v = ((const float4*)src)[off];
  ushort4 o;
  o.x = rnbf(v.x); o.y = rnbf(v.y); o.z = rnbf(v.z); o.w = rnbf(v.w);
  ((ushort4*)dst)[off] = o;
}

// ---------------------------------------------------------------------------
// Pipelined MFMA GEMM core: C 128x256 tile = A[128xK] x B[256xK]^T, K=1024.
// 8 waves (2M x 4N). BK=32 slabs, 3-deep rotation (72 KB LDS, 2 blocks/CU).
// Per phase: VMW(3), barrier, 8 ds_read_b128 (chunk-XOR swizzled), stage
// slot t+2, 16 MFMA (setprio-wrapped). Proven 844 TF (R6/R11). R9/R10
// falsified the 256x256 deep pipeline at this shape. R7: launch_bounds
// min-waves stays <=4 — (512,6) caps VGPR ~85 and spills acc.
// ---------------------------------------------------------------------------
#define STG(sl_, tt_) { \
  gload_lds16(Asrc + (tt_) * 32, &lds[(sl_) * 4096 + tid * 8]); \
  gload_lds16(Bsrc0 + (tt_) * 32, &lds[12288 + (sl_) * 8192 + tid * 8]); \
  gload_lds16(Bsrc1 + (tt_) * 32, &lds[12288 + (sl_) * 8192 + 4096 + tid * 8]); }

#define LDFRAGS(sl_) \
  const ushort* pa = &lds[(sl_) * 4096 + aOff]; \
  a0 = *(const bf16x8*)pa;          a1 = *(const bf16x8*)(pa + 512); \
  a2 = *(const bf16x8*)(pa + 1024); a3 = *(const bf16x8*)(pa + 1536); \
  const ushort* pb = &lds[12288 + (sl_) * 8192 + bOff]; \
  b0 = *(const bf16x8*)pb;          b1 = *(const bf16x8*)(pb + 512); \
  b2 = *(const bf16x8*)(pb + 1024); b3 = *(const bf16x8*)(pb + 1536);

#define MM(i, j, A_, B_) \
  acc[i][j] = __builtin_amdgcn_mfma_f32_16x16x32_bf16(A_, B_, acc[i][j], 0, 0, 0)
#define MFMA16() do { __builtin_amdgcn_s_setprio(1); \
  MM(0,0,a0,b0); MM(0,1,a0,b1); MM(0,2,a0,b2); MM(0,3,a0,b3); \
  MM(1,0,a1,b0); MM(1,1,a1,b1); MM(1,2,a1,b2); MM(1,3,a1,b3); \
  MM(2,0,a2,b0); MM(2,1,a2,b1); MM(2,2,a2,b2); MM(2,3,a2,b3); \
  MM(3,0,a3,b0); MM(3,1,a3,b1); MM(3,2,a3,b2); MM(3,3,a3,b3); \
  __builtin_amdgcn_s_setprio(0); } while (0)

__device__ __forceinline__ void pipe_gemm(const ushort* __restrict__ Ag,
                                          const ushort* __restrict__ Bg,
                                          ushort* lds, f32x4 acc[4][4]) {
  const int tid = threadIdx.x;
  const int l = tid & 63, wv = tid >> 6;
  const int wm = wv >> 2, wn = wv & 3;
  const int c16 = l & 15, g4 = l >> 4;
  const int gch = (tid & 3) ^ ((tid >> 3) & 3);
  const ushort* Asrc = Ag + (size_t)(tid >> 2) * 1024 + gch * 8;
  const ushort* Bsrc0 = Bg + (size_t)(tid >> 2) * 1024 + gch * 8;
  const ushort* Bsrc1 = Bsrc0 + (size_t)128 * 1024;
  const int xq = (c16 >> 1) & 3;
  const int aOff = (wm * 64 + c16) * 32 + ((g4 ^ xq) << 3);
  const int bOff = (wn * 64 + c16) * 32 + ((g4 ^ xq) << 3);

  STG(0, 0);
  STG(1, 1);
  int sl = 0;
#pragma unroll 3
  for (int t = 0; t < 30; ++t) {
    const int slN = sl ? sl - 1 : 2;  // (sl+2)%3
    VMW(3); BARR();
    bf16x8 a0, a1, a2, a3, b0, b1, b2, b3;
    LDFRAGS(sl);
    STG(slN, t + 2);
    MFMA16();
    sl = (sl == 2) ? 0 : sl + 1;
  }
  {  // t=30, slab 0
    VMW(3); BARR();
    bf16x8 a0, a1, a2, a3, b0, b1, b2, b3;
    LDFRAGS(0);
    MFMA16();
  }
  {  // t=31, slab 1
    VMW(0); BARR();
    bf16x8 a0, a1, a2, a3, b0, b1, b2, b3;
    LDFRAGS(1);
    MFMA16();
  }
}

// ---------------------------------------------------------------------------
// Kernel 1 (R14: PERSISTENT): qkv = x @ w_attn^T; phi on q,k; q/k row-major,
// kT/vT via per-wave LDS transpose, z chunk-partials fused.
// Grid 512 = exact residency (2 blocks/CU x 256 CU). Each block serves its
// XCD partition (b&7) from an atomic per-XCD tile queue of 96 tiles
// (bm-fastest: bm = xcd*8 + (t&7), bn = t>>3 — preserves R6's L2 mapping).
// Removes the 1.5-dispatch-round tail (R11-R13: Occupancy 35% = half-empty
// round 2). Counters are memset per launch (graph-safe); output is
// deterministic (each tile computed exactly once, disjoint stores).
// __syncthreads at loop head orders the tile broadcast AND drains the
// previous epilogue's LDS-scratch reads before the next prologue's
// global_load_lds overwrite.
// ---------------------------------------------------------------------------
__global__ __launch_bounds__(512, 4) void k_qkv2(
    const ushort* __restrict__ xb, const ushort* __restrict__ wab,
    ushort* __restrict__ qg, ushort* __restrict__ kg,
    ushort* __restrict__ ktg, ushort* __restrict__ vtg,
    float* __restrict__ zp, unsigned* __restrict__ ctrs) {
  extern __shared__ ushort lds[];
  __shared__ unsigned tile_s;
  const int xcd = blockIdx.x & 7;
  const int tid = threadIdx.x;
  const int wv = tid >> 6, l = tid & 63;
  const int wm = wv >> 2, wn = wv & 3;
  const int c16 = l & 15, g4 = l >> 4;

  for (;;) {
    if (tid == 0) tile_s = atomicAdd(&ctrs[xcd], 1u);
    __syncthreads();  // broadcast tile; drain prior epilogue LDS reads
    const unsigned t = tile_s;
    if (t >= 96u) break;
    const int bm = xcd * 8 + (int)(t & 7u);   // [0,64)
    const int bn = (int)(t >> 3);             // [0,12)

    f32x4 acc[4][4] = {};
    pipe_gemm(xb + (size_t)bm * 128 * 1024, wab + (size_t)bn * 256 * 1024,
              lds, acc);

    // ---- epilogue ----
    BARR();  // pipeline LDS reads done; LDS reused as transpose buffers
    const int colbase = bn * 256 + wn * 64;
    const int which = colbase >> 10;
    const int h = (colbase & 1023) >> 6;
    const int rowbase = bm * 128 + wm * 64;
    const int bidx = rowbase >> 11;
    const int tbase = rowbase & 2047;
    const size_t bh = (size_t)(bidx * 16 + h);
    ushort* wlds = &lds[wv * 4096];  // per-wave 64d x 64t transpose tile
    float zpart[4] = {0.f, 0.f, 0.f, 0.f};
#pragma unroll
    for (int mf = 0; mf < 4; ++mf) {
#pragma unroll
      for (int nf = 0; nf < 4; ++nf) {
        float o[4];
#pragma unroll
        for (int j = 0; j < 4; ++j) {
          float u = acc[mf][nf][j];
          o[j] = (which < 2) ? ((u > 0.f) ? u + 1.f : expf(u)) : u;  // elu+1
        }
        const int d = nf * 16 + c16;
        if (which == 1) zpart[nf] += o[0] + o[1] + o[2] + o[3];
        if (which <= 1) {
          ushort* dst = (which == 0) ? qg : kg;
          const size_t rb = (bh * 2048 + tbase + mf * 16 + g4 * 4) * 64 + d;
#pragma unroll
          for (int j = 0; j < 4; ++j) dst[rb + (size_t)j * 64] = rnbf(o[j]);
        }
        if (which >= 1) {
          const int tb = (mf * 4 + g4) ^ ((d & 3) << 1);
          ushort4 pk;
          pk.x = rnbf(o[0]); pk.y = rnbf(o[1]); pk.z = rnbf(o[2]); pk.w = rnbf(o[3]);
          *(ushort4*)&wlds[d * 64 + tb * 4] = pk;
        }
      }
    }
    if (which == 1) {
      const int cc = tbase >> 7;
#pragma unroll
      for (int nf = 0; nf < 4; ++nf) {
        float zz = zpart[nf];
        zz += __shfl_xor(zz, 16);
        zz += __shfl_xor(zz, 32);
        if (l < 16) zp[((bh * NC_ + cc) * 2 + wm) * 64 + nf * 16 + l] = zz;
      }
    }
    if (which >= 1) {
      LGK0();  // wave-local ds_writes visible to this wave's reads
      ushort* tg = (which == 1) ? ktg : vtg;
#pragma unroll
      for (int it = 0; it < 8; ++it) {
        const int d = it * 8 + (l >> 3);
        const int t0 = (l & 7) * 8;
        const int blk = ((l & 7) * 2) ^ ((d & 3) << 1);
        bf16x8 vv_ = *(const bf16x8*)&wlds[d * 64 + blk * 4];
        *(bf16x8*)&tg[(bh * 64 + d) * 2048 + tbase + t0] = vv_;
      }
      LGK0();  // reads done before next tile's staging overwrites LDS
    }
  }
}

// ---------------------------------------------------------------------------
// Kernel 5 (k_proj3): out = y @ w_proj^T. 128x128 tile, 256 threads
// (4 waves, 2x2 of 64x64), BK=32, 3-slab 48 KB LDS; grid 64x8 = 512.
// Same chunk-XOR swizzle / counted-vmcnt structure; 4 loads/stage -> VMW(4).
// ---------------------------------------------------------------------------
#define APB(sl_) ((sl_) * 4096)
#define BPB(sl_) (12288 + (sl_) * 4096)

#define STGP(sl_, tt_) { \
  gload_lds16(Asrc + (tt_) * 32,         &lds[APB(sl_) + tid * 8]); \
  gload_lds16(Asrc + (tt_) * 32 + 65536, &lds[APB(sl_) + 2048 + tid * 8]); \
  gload_lds16(Bsrc + (tt_) * 32,         &lds[BPB(sl_) + tid * 8]); \
  gload_lds16(Bsrc + (tt_) * 32 + 65536, &lds[BPB(sl_) + 2048 + tid * 8]); }

#define LDFRAGSP(sl_) \
  const ushort* pa = &lds[APB(sl_) + aOff]; \
  a0 = *(const bf16x8*)pa;          a1 = *(const bf16x8*)(pa + 512); \
  a2 = *(const bf16x8*)(pa + 1024); a3 = *(const bf16x8*)(pa + 1536); \
  const ushort* pb = &lds[BPB(sl_) + bOff]; \
  b0 = *(const bf16x8*)pb;          b1 = *(const bf16x8*)(pb + 512); \
  b2 = *(const bf16x8*)(pb + 1024); b3 = *(const bf16x8*)(pb + 1536);

__global__ __launch_bounds__(256, 2) void k_proj3(
    const ushort* __restrict__ yb, const ushort* __restrict__ wpb,
    float* __restrict__ out) {
  extern __shared__ ushort lds[];
  const int b = blockIdx.x;
  const int xcd = b & 7, idx = b >> 3;     // idx in [0,64)
  const int bm = xcd * 8 + (idx & 7);      // [0,64)
  const int bn = idx >> 3;                 // [0,8)
  const int tid = threadIdx.x;
  const int wv = tid >> 6, l = tid & 63;
  const int wm = wv >> 1, wn = wv & 1;
  const int c16 = l & 15, g4 = l >> 4;

  const ushort* Ag = yb + (size_t)bm * 128 * 1024;
  const ushort* Bg = wpb + (size_t)bn * 128 * 1024;
  const int gch = (tid & 3) ^ ((tid >> 3) & 3);
  const ushort* Asrc = Ag + (size_t)(tid >> 2) * 1024 + gch * 8;
  const ushort* Bsrc = Bg + (size_t)(tid >> 2) * 1024 + gch * 8;
  const int xq = (c16 >> 1) & 3;
  const int aOff = (wm * 64 + c16) * 32 + ((g4 ^ xq) << 3);
  const int bOff = (wn * 64 + c16) * 32 + ((g4 ^ xq) << 3);

  f32x4 acc[4][4] = {};

  STGP(0, 0);
  STGP(1, 1);
  int sl = 0;
#pragma unroll 3
  for (int t = 0; t < 30; ++t) {
    const int slN = sl ? sl - 1 : 2;  // (sl+2)%3
    VMW(4); BARR();
    bf16x8 a0, a1, a2, a3, b0, b1, b2, b3;
    LDFRAGSP(sl);
    STGP(slN, t + 2);
    MFMA16();
    sl = (sl == 2) ? 0 : sl + 1;
  }
  {  // t=30, slab 0
    VMW(4); BARR();
    bf16x8 a0, a1, a2, a3, b0, b1, b2, b3;
    LDFRAGSP(0);
    MFMA16();
  }
  {  // t=31, slab 1
    VMW(0); BARR();
    bf16x8 a0, a1, a2, a3, b0, b1, b2, b3;
    LDFRAGSP(1);
    MFMA16();
  }

  const int rowbase = bm * 128 + wm * 64 + g4 * 4;
  const int colbase = bn * 128 + wn * 64 + c16;
#pragma unroll
  for (int mf = 0; mf < 4; ++mf)
#pragma unroll
    for (int nf = 0; nf < 4; ++nf) {
      const size_t base = (size_t)(rowbase + mf * 16) * 1024 + colbase + nf * 16;
#pragma unroll
      for (int j = 0; j < 4; ++j)
        out[base + (size_t)j * 1024] = acc[mf][nf][j];
    }
}

// ---------------------------------------------------------------------------
// Kernel 2 (MFMA): per-chunk  ST[e][d] = sum_t v[t][e] k[t][d]  (fp32 out)
// ---------------------------------------------------------------------------
__global__ __launch_bounds__(256) void k_stats(const ushort* __restrict__ ktg,
                                               const ushort* __restrict__ vtg,
                                               float* __restrict__ Sc) {
  __shared__ __align__(16) ushort kT_s[64 * 128], vT_s[64 * 128];
  const int blk = blockIdx.x;
  const int bh = blk >> 4, c = blk & 15;
  const int tid = threadIdx.x;
  const int w = tid >> 6, l = tid & 63;
  const ushort* ktb = ktg + (size_t)bh * D_ * T_ + c * CHUNK_;
  const ushort* vtb = vtg + (size_t)bh * D_ * T_ + c * CHUNK_;
#pragma unroll
  for (int s2 = 0; s2 < 4; ++s2) {
    const int seg = w * 4 + s2;
    const int row = seg * 4 + (l >> 4);
    const int sb = ((l & 15) ^ (row & 7)) * 8;
    gload_lds16(ktb + (size_t)row * T_ + sb, &kT_s[seg * 512]);
    gload_lds16(vtb + (size_t)row * T_ + sb, &vT_s[seg * 512]);
  }
  __syncthreads();
  const int wr = w >> 1, wc = w & 1;
  f32x4 acc[2][2] = {};
#pragma unroll
  for (int kt = 0; kt < 4; ++kt) {
    const int g = kt * 32 + (l >> 4) * 8;
    bf16x8 av[2], bk[2];
#pragma unroll
    for (int rt = 0; rt < 2; ++rt) {
      const int e = wr * 32 + rt * 16 + (l & 15);
      av[rt] = *(const bf16x8*)&vT_s[e * 128 + (g ^ ((e & 7) << 3))];
    }
#pragma unroll
    for (int ct = 0; ct < 2; ++ct) {
      const int d = wc * 32 + ct * 16 + (l & 15);
      bk[ct] = *(const bf16x8*)&kT_s[d * 128 + (g ^ ((d & 7) << 3))];
    }
#pragma unroll
    for (int rt = 0; rt < 2; ++rt)
#pragma unroll
      for (int ct = 0; ct < 2; ++ct)
        acc[rt][ct] = __builtin_amdgcn_mfma_f32_16x16x32_bf16(av[rt], bk[ct],
                                                              acc[rt][ct], 0, 0, 0);
  }
  float* So = Sc + (size_t)blk * 4096;
#pragma unroll
  for (int rt = 0; rt < 2; ++rt)
#pragma unroll
    for (int ct = 0; ct < 2; ++ct)
#pragma unroll
      for (int jj = 0; jj < 4; ++jj)
        So[(wr * 32 + rt * 16 + (l >> 4) * 4 + jj) * 64 + wc * 32 + ct * 16 + (l & 15)] =
            acc[rt][ct][jj];
}

// ---------------------------------------------------------------------------
// Kernel 3: exclusive prefix over 16 chunks, parallelized.
// blocks 0..255: (bh, quarter) S-scan; blocks 256..319: z-scan per bh
// (z partials come in 2 halves per chunk from k_qkv2's wm split).
// ---------------------------------------------------------------------------
__global__ __launch_bounds__(256) void k_prefix2(const float* __restrict__ Sc,
                                                 ushort* __restrict__ STb,
                                                 const float* __restrict__ zp,
                                                 float* __restrict__ zout) {
  const int b = blockIdx.x;
  const int tid = threadIdx.x;
  if (b < 256) {
    const int bh = b >> 2, qt = b & 3;
    const float4* Sb = (const float4*)(Sc + (size_t)bh * NC_ * 4096) + qt * 256 + tid;
    ushort4* Ob = (ushort4*)(STb + (size_t)bh * NC_ * 4096) + qt * 256 + tid;
    float4 v[16];
#pragma unroll
    for (int c = 0; c < NC_; ++c) v[c] = Sb[c * 1024];
    float4 acc = make_float4(0.f, 0.f, 0.f, 0.f);
#pragma unroll
    for (int c = 0; c < NC_; ++c) {
      ushort4 o;
      o.x = rnbf(acc.x); o.y = rnbf(acc.y); o.z = rnbf(acc.z); o.w = rnbf(acc.w);
      Ob[c * 1024] = o;
      acc.x += v[c].x; acc.y += v[c].y; acc.z += v[c].z; acc.w += v[c].w;
    }
  } else {
    const int bh = b - 256;
    if (tid < 16) {
      const float4* zpb = (const float4*)(zp + (size_t)bh * NC_ * 128);
      float4* zob = (float4*)(zout + (size_t)bh * NC_ * 64);
      float4 t0[16], t1[16];
#pragma unroll
      for (int c = 0; c < NC_; ++c) {
        t0[c] = zpb[c * 32 + tid];
        t1[c] = zpb[c * 32 + 16 + tid];
      }
      float4 za = make_float4(0.f, 0.f, 0.f, 0.f);
#pragma unroll
      for (int c = 0; c < NC_; ++c) {
        zob[c * 16 + tid] = za;
        za.x += t0[c].x + t1[c].x; za.y += t0[c].y + t1[c].y;
        za.z += t0[c].z + t1[c].z; za.w += t0[c].w + t1[c].w;
      }
    }
  }
}

// ---------------------------------------------------------------------------
// Kernel 4 (MFMA): per-chunk output -> y bf16 [B,T,H,D].
// CAUSAL-AWARE (R12): wave w computes only key blocks jt <= w; even waves
// zero-fill the jt=w+1 strip; wave-local LDS fence instead of 2nd barrier.
// ---------------------------------------------------------------------------
__global__ __launch_bounds__(512, 4) void k_out(
    const ushort* __restrict__ qg, const ushort* __restrict__ kg,
    const ushort* __restrict__ vtg, const ushort* __restrict__ STb,
    const float* __restrict__ zg, ushort* __restrict__ yb) {
  __shared__ __align__(16) ushort k_s[128 * 64];
  __shared__ __align__(16) ushort vT_s[64 * 128];
  __shared__ __align__(16) ushort ST_s[64 * 64];
  __shared__ __align__(16) ushort P_s[128 * 128];
  __shared__ float z_s[64];
  __shared__ float dinter_s[128];
  const int blk = blockIdx.x;
  const int bh = blk >> 4, c = blk & 15;
  const int tid = threadIdx.x;
  const int w = tid >> 6, l = tid & 63;

  const ushort* kbase = kg + ((size_t)bh * T_ + c * CHUNK_) * D_;
  const ushort* vbase = vtg + (size_t)bh * D_ * T_ + c * CHUNK_;
  const ushort* sbase = STb + ((size_t)bh * NC_ + c) * 4096;
  {
    int seg = w, row = seg * 8 + (l >> 3);
    gload_lds16(kbase + (size_t)row * 64 + ((l & 7) ^ (row & 7)) * 8, &k_s[seg * 512]);
    seg = w + 8; row = seg * 8 + (l >> 3);
    gload_lds16(kbase + (size_t)row * 64 + ((l & 7) ^ (row & 7)) * 8, &k_s[seg * 512]);
  }
  {
    int seg = w, row = seg * 4 + (l >> 4);
    gload_lds16(vbase + (size_t)row * T_ + ((l & 15) ^ (row & 7)) * 8, &vT_s[seg * 512]);
    seg = w + 8; row = seg * 4 + (l >> 4);
    gload_lds16(vbase + (size_t)row * T_ + ((l & 15) ^ (row & 7)) * 8, &vT_s[seg * 512]);
  }
  {
    const int seg = w, row = seg * 8 + (l >> 3);
    gload_lds16(sbase + (size_t)row * 64 + ((l & 7) ^ (row & 7)) * 8, &ST_s[seg * 512]);
  }
  if (tid < 64) z_s[tid] = zg[((size_t)bh * NC_ + c) * 64 + tid];
  const int arow = w * 16 + (l & 15);
  const ushort* qrow = qg + ((size_t)bh * T_ + c * CHUNK_ + arow) * D_ + (l >> 4) * 8;
  bf16x8 qf0 = *(const bf16x8*)(qrow);
  bf16x8 qf1 = *(const bf16x8*)(qrow + 32);
  __syncthreads();

  // ---- causal QK^T: wave w only needs key blocks jt <= w ----
  const int crow0 = w * 16 + (l >> 4) * 4;
  float rsum[4] = {0.f, 0.f, 0.f, 0.f};
  for (int jt = 0; jt <= w; ++jt) {
    const int j = jt * 16 + (l & 15);
    const int sw = (j & 7) << 3, g = (l >> 4) * 8;
    bf16x8 b0 = *(const bf16x8*)&k_s[j * 64 + (g ^ sw)];
    bf16x8 b1 = *(const bf16x8*)&k_s[j * 64 + ((g + 32) ^ sw)];
    f32x4 s4 = {0.f, 0.f, 0.f, 0.f};
    s4 = __builtin_amdgcn_mfma_f32_16x16x32_bf16(qf0, b0, s4, 0, 0, 0);
    s4 = __builtin_amdgcn_mfma_f32_16x16x32_bf16(qf1, b1, s4, 0, 0, 0);
#pragma unroll
    for (int jj = 0; jj < 4; ++jj) {
      const int i = crow0 + jj;
      float s = (j <= i) ? s4[jj] : 0.f;
      rsum[jj] += s;
      P_s[i * 128 + (j ^ ((i & 7) << 3))] = rnbf(s);
    }
  }
  if (!(w & 1)) {  // even wave: zero-fill jt=w+1 so PV's boundary 32-block is defined
    const int j = (w + 1) * 16 + (l & 15);
#pragma unroll
    for (int jj = 0; jj < 4; ++jj) {
      const int i = crow0 + jj;
      P_s[i * 128 + (j ^ ((i & 7) << 3))] = 0;
    }
  }
  float di = 0.f;
#pragma unroll
  for (int jj = 0; jj < 8; ++jj) {
    di = fmaf(bf2f(qf0[jj]), z_s[(l >> 4) * 8 + jj], di);
    di = fmaf(bf2f(qf1[jj]), z_s[32 + (l >> 4) * 8 + jj], di);
  }
  di += __shfl_xor(di, 16);
  di += __shfl_xor(di, 32);
  if (l < 16) dinter_s[w * 16 + l] = di;
#pragma unroll
  for (int jj = 0; jj < 4; ++jj) {
    float r = rsum[jj];
    r += __shfl_xor(r, 1); r += __shfl_xor(r, 2);
    r += __shfl_xor(r, 4); r += __shfl_xor(r, 8);
    rsum[jj] = r;
  }
  // P_s / dinter_s rows are wave-local: wave-level LDS fence suffices.
  LGK0();

  f32x4 acc2[4] = {};
#pragma unroll
  for (int et = 0; et < 4; ++et) {
    const int e = et * 16 + (l & 15);
    const int sw = (e & 7) << 3, g = (l >> 4) * 8;
    bf16x8 s0 = *(const bf16x8*)&ST_s[e * 64 + (g ^ sw)];
    bf16x8 s1 = *(const bf16x8*)&ST_s[e * 64 + ((g + 32) ^ sw)];
    acc2[et] = __builtin_amdgcn_mfma_f32_16x16x32_bf16(qf0, s0, acc2[et], 0, 0, 0);
    acc2[et] = __builtin_amdgcn_mfma_f32_16x16x32_bf16(qf1, s1, acc2[et], 0, 0, 0);
  }
  const int prow = w * 16 + (l & 15);
  const int psw = (prow & 7) << 3;
  for (int jkt = 0; jkt <= (w >> 1); ++jkt) {
    bf16x8 pa = *(const bf16x8*)&P_s[prow * 128 + ((jkt * 32 + (l >> 4) * 8) ^ psw)];
#pragma unroll
    for (int et = 0; et < 4; ++et) {
      const int e = et * 16 + (l & 15);
      bf16x8 bv = *(const bf16x8*)&vT_s[e * 128 +
                                        ((jkt * 32 + (l >> 4) * 8) ^ ((e & 7) << 3))];
      acc2[et] = __builtin_amdgcn_mfma_f32_16x16x32_bf16(pa, bv, acc2[et], 0, 0, 0);
    }
  }
  float inv[4];
#pragma unroll
  for (int jj = 0; jj < 4; ++jj)
    inv[jj] = 1.0f / (rsum[jj] + dinter_s[crow0 + jj] + 1e-6f);
  const int b = bh >> 4, h = bh & 15;
#pragma unroll
  for (int et = 0; et < 4; ++et) {
    const int d = et * 16 + (l & 15);
#pragma unroll
    for (int jj = 0; jj < 4; ++jj) {
      const int t = c * CHUNK_ + crow0 + jj;
      yb[((size_t)(b * T_ + t) * H_ + h) * D_ + d] = rnbf(acc2[et][jj] * inv[jj]);
    }
  }
}

// ---------------------------------------------------------------------------
extern "C" void kernel_launch(void* const* d_in, const int* in_sizes, int n_in,
                              void* d_out, int out_size, void* d_ws, size_t ws_size,
                              hipStream_t stream) {
  const float* x = (const float*)d_in[0];
  const float* w_attn = (const float*)d_in[1];
  const float* w_proj = (const float*)d_in[2];
  float* out = (float*)d_out;

  ushort* xb = (ushort*)d_ws;                        // [8192,1024]
  ushort* wab = xb + (size_t)M_ * E_;                // [3072,1024]
  ushort* wpb = wab + (size_t)3 * E_ * E_;           // [1024,1024]
  ushort* qb = wpb + (size_t)E_ * E_;                // [bh][t][d]
  ushort* kbm = qb + (size_t)M_ * E_;                // [bh][t][d]
  ushort* kT = kbm + (size_t)M_ * E_;                // [bh][d][t]
  ushort* vT = kT + (size_t)M_ * E_;                 // [bh][d][t]
  ushort* yb = vT + (size_t)M_ * E_;                 // [B,T,H,D]
  ushort* STb = yb + (size_t)M_ * E_;                // [bh][c][e][d] bf16
  float* Schunk = (float*)(STb + (size_t)BH_ * NC_ * 4096);  // fp32
  float* zpart = Schunk + (size_t)BH_ * NC_ * 4096;  // [bh][c][2][64]
  float* zout = zpart + (size_t)BH_ * NC_ * 2 * 64;  // [bh][c][64]
  unsigned* ctrs = (unsigned*)(zout + (size_t)BH_ * NC_ * 64);  // 8 uints

  hipMemsetAsync(ctrs, 0, 8 * sizeof(unsigned), stream);
  k_cvt3<<<12288, 256, 0, stream>>>(x, w_attn, w_proj, xb, wab, wpb);

  hipFuncSetAttribute((const void*)k_qkv2,
                      hipFuncAttributeMaxDynamicSharedMemorySize, 73728);
  hipFuncSetAttribute((const void*)k_proj3,
                      hipFuncAttributeMaxDynamicSharedMemorySize, 49152);

  k_qkv2<<<512, 512, 73728, stream>>>(xb, wab, qb, kbm, kT, vT, zpart, ctrs);
  k_stats<<<1024, 256, 0, stream>>>(kT, vT, Schunk);
  k_prefix2<<<320, 256, 0, stream>>>(Schunk, STb, zpart, zout);
  k_out<<<1024, 512, 0, stream>>>(qb, kbm, vT, STb, zout, yb);
  k_proj3<<<512, 256, 49152, stream>>>(yb, wpb, out);
}

// Round 15
// 127.280 us; speedup vs baseline: 2.1457x; 2.1457x over previous
//
#include <hip/hip_runtime.h>
#include <math.h>

#define B_ 4
#define T_ 2048
#define E_ 1024
#define H_ 16
#define D_ 64
#define CHUNK_ 128
#define NC_ 16
#define BH_ (B_ * H_)   // 64
#define M_ (B_ * T_)    // 8192

typedef __attribute__((ext_vector_type(8))) short bf16x8;
typedef __attribute__((ext_vector_type(4))) float f32x4;

__device__ __forceinline__ ushort rnbf(float f) {
  unsigned u = __float_as_uint(f);
  unsigned r = (u + 0x7FFFu + ((u >> 16) & 1u)) >> 16;
  return (ushort)r;
}

__device__ __forceinline__ float bf2f(short s) {
  return __uint_as_float(((unsigned)(ushort)s) << 16);
}

__device__ __forceinline__ void gload_lds16(const void* g, void* l) {
  __builtin_amdgcn_global_load_lds(
      (const __attribute__((address_space(1))) unsigned int*)g,
      (__attribute__((address_space(3))) unsigned int*)l, 16, 0, 0);
}

#define VMW(N) do { asm volatile("s_waitcnt vmcnt(" #N ")" ::: "memory"); \
                    __builtin_amdgcn_sched_barrier(0); } while (0)
#define BARR() do { __builtin_amdgcn_s_barrier(); \
                    __builtin_amdgcn_sched_barrier(0); } while (0)
#define LGK0() do { asm volatile("s_waitcnt lgkmcnt(0)" ::: "memory"); \
                    __builtin_amdgcn_sched_barrier(0); } while (0)

// ---------------------------------------------------------------------------
// fused fp32 -> bf16 conversion (grid-stride, 2048 blocks per G11).
// R14 lesson: persistent/atomic work queues poison the counted-vmcnt GEMM
// pipeline (per-tile vmcnt(0) drains + epilogue stores in the VMEM queue) —
// 61->212us. Static partitioning only.
// ---------------------------------------------------------------------------
#define N4X_ (M_ * E_ / 4)           // 2097152
#define N4A_ (3 * E_ * E_ / 4)       // 786432
#define N4P_ (E_ * E_ / 4)           // 262144
#define N4TOT_ (N4X_ + N4A_ + N4P_)  // 3145728
__global__ __launch_bounds__(256) void k_cvt3(
    const float* __restrict__ x, const float* __restrict__ wa,
    const float* __restrict__ wp, ushort* __restrict__ xb,
    ushort* __restrict__ wab, ushort* __restrict__ wpb) {
  for (int i = blockIdx.x * 256 + threadIdx.x; i < N4TOT_; i += 2048 * 256) {
    const float* src;
    ushort* dst;
    int off;
    if (i < N4X_) { src = x; dst = xb; off = i; }
    else if (i < N4X_ + N4A_) { src = wa; dst = wab; off = i - N4X_; }
    else { src = wp; dst = wpb; off = i - (N4X_ + N4A_); }
    float4 v = ((const float4*)src)[off];
    ushort4 o;
    o.x = rnbf(v.x); o.y = rnbf(v.y); o.z = rnbf(v.z); o.w = rnbf(v.w);
    ((ushort4*)dst)[off] = o;
  }
}

// ---------------------------------------------------------------------------
// Pipelined MFMA GEMM core: C 128x256 tile = A[128xK] x B[256xK]^T, K=1024.
// 8 waves (2M x 4N). BK=32 slabs, 3-deep rotation (72 KB LDS, 2 blocks/CU).
// Per phase: VMW(3), barrier, 8 ds_read_b128 (chunk-XOR swizzled), stage
// slot t+2, 16 MFMA (setprio-wrapped). Proven 844 TF (R6/R11/R13), ~94% of
// the 2-barrier structure ceiling. Falsified alternatives: 256x256 deep
// pipeline (R9/R10: 1.5-round tail @1blk/CU), 3-blk/CU 2-slab (R8: neutral),
// persistent queue (R14: 3.5x regression). R7: launch_bounds min-waves <=4.
// ---------------------------------------------------------------------------
#define STG(sl_, tt_) { \
  gload_lds16(Asrc + (tt_) * 32, &lds[(sl_) * 4096 + tid * 8]); \
  gload_lds16(Bsrc0 + (tt_) * 32, &lds[12288 + (sl_) * 8192 + tid * 8]); \
  gload_lds16(Bsrc1 + (tt_) * 32, &lds[12288 + (sl_) * 8192 + 4096 + tid * 8]); }

#define LDFRAGS(sl_) \
  const ushort* pa = &lds[(sl_) * 4096 + aOff]; \
  a0 = *(const bf16x8*)pa;          a1 = *(const bf16x8*)(pa + 512); \
  a2 = *(const bf16x8*)(pa + 1024); a3 = *(const bf16x8*)(pa + 1536); \
  const ushort* pb = &lds[12288 + (sl_) * 8192 + bOff]; \
  b0 = *(const bf16x8*)pb;          b1 = *(const bf16x8*)(pb + 512); \
  b2 = *(const bf16x8*)(pb + 1024); b3 = *(const bf16x8*)(pb + 1536);

#define MM(i, j, A_, B_) \
  acc[i][j] = __builtin_amdgcn_mfma_f32_16x16x32_bf16(A_, B_, acc[i][j], 0, 0, 0)
#define MFMA16() do { __builtin_amdgcn_s_setprio(1); \
  MM(0,0,a0,b0); MM(0,1,a0,b1); MM(0,2,a0,b2); MM(0,3,a0,b3); \
  MM(1,0,a1,b0); MM(1,1,a1,b1); MM(1,2,a1,b2); MM(1,3,a1,b3); \
  MM(2,0,a2,b0); MM(2,1,a2,b1); MM(2,2,a2,b2); MM(2,3,a2,b3); \
  MM(3,0,a3,b0); MM(3,1,a3,b1); MM(3,2,a3,b2); MM(3,3,a3,b3); \
  __builtin_amdgcn_s_setprio(0); } while (0)

__device__ __forceinline__ void pipe_gemm(const ushort* __restrict__ Ag,
                                          const ushort* __restrict__ Bg,
                                          ushort* lds, f32x4 acc[4][4]) {
  const int tid = threadIdx.x;
  const int l = tid & 63, wv = tid >> 6;
  const int wm = wv >> 2, wn = wv & 3;
  const int c16 = l & 15, g4 = l >> 4;
  const int gch = (tid & 3) ^ ((tid >> 3) & 3);
  const ushort* Asrc = Ag + (size_t)(tid >> 2) * 1024 + gch * 8;
  const ushort* Bsrc0 = Bg + (size_t)(tid >> 2) * 1024 + gch * 8;
  const ushort* Bsrc1 = Bsrc0 + (size_t)128 * 1024;
  const int xq = (c16 >> 1) & 3;
  const int aOff = (wm * 64 + c16) * 32 + ((g4 ^ xq) << 3);
  const int bOff = (wn * 64 + c16) * 32 + ((g4 ^ xq) << 3);

  STG(0, 0);
  STG(1, 1);
  int sl = 0;
#pragma unroll 3
  for (int t = 0; t < 30; ++t) {
    const int slN = sl ? sl - 1 : 2;  // (sl+2)%3
    VMW(3); BARR();
    bf16x8 a0, a1, a2, a3, b0, b1, b2, b3;
    LDFRAGS(sl);
    STG(slN, t + 2);
    MFMA16();
    sl = (sl == 2) ? 0 : sl + 1;
  }
  {  // t=30, slab 0
    VMW(3); BARR();
    bf16x8 a0, a1, a2, a3, b0, b1, b2, b3;
    LDFRAGS(0);
    MFMA16();
  }
  {  // t=31, slab 1
    VMW(0); BARR();
    bf16x8 a0, a1, a2, a3, b0, b1, b2, b3;
    LDFRAGS(1);
    MFMA16();
  }
}

// ---------------------------------------------------------------------------
// Kernel 1: qkv = x @ w_attn^T; phi on q,k; q/k row-major, kT/vT transposed
// (per-wave LDS transpose), z chunk-partials fused.
// XCD-L2 mapping: xcd = b&7 owns bm slice [xcd*8, xcd*8+8), bm-fastest ->
// A slice (2 MB) L2-resident, B panel shared by co-running bm-blocks.
// ---------------------------------------------------------------------------
__global__ __launch_bounds__(512, 4) void k_qkv2(
    const ushort* __restrict__ xb, const ushort* __restrict__ wab,
    ushort* __restrict__ qg, ushort* __restrict__ kg,
    ushort* __restrict__ ktg, ushort* __restrict__ vtg,
    float* __restrict__ zp) {
  extern __shared__ ushort lds[];
  const int b = blockIdx.x;
  const int xcd = b & 7, idx = b >> 3;     // idx in [0,96)
  const int bm = xcd * 8 + (idx & 7);      // [0,64)
  const int bn = idx >> 3;                 // [0,12)
  const int tid = threadIdx.x;
  const int wv = tid >> 6, l = tid & 63;
  const int wm = wv >> 2, wn = wv & 3;
  const int c16 = l & 15, g4 = l >> 4;

  f32x4 acc[4][4] = {};
  pipe_gemm(xb + (size_t)bm * 128 * 1024, wab + (size_t)bn * 256 * 1024, lds, acc);

  // ---- epilogue ----
  BARR();  // pipeline LDS reads done; LDS reused as transpose buffers
  const int colbase = bn * 256 + wn * 64;
  const int which = colbase >> 10;
  const int h = (colbase & 1023) >> 6;
  const int rowbase = bm * 128 + wm * 64;
  const int bidx = rowbase >> 11;
  const int tbase = rowbase & 2047;
  const size_t bh = (size_t)(bidx * 16 + h);
  ushort* wlds = &lds[wv * 4096];  // per-wave 64d x 64t transpose tile
  float zpart[4] = {0.f, 0.f, 0.f, 0.f};
#pragma unroll
  for (int mf = 0; mf < 4; ++mf) {
#pragma unroll
    for (int nf = 0; nf < 4; ++nf) {
      float o[4];
#pragma unroll
      for (int j = 0; j < 4; ++j) {
        float u = acc[mf][nf][j];
        o[j] = (which < 2) ? ((u > 0.f) ? u + 1.f : expf(u)) : u;  // elu+1
      }
      const int d = nf * 16 + c16;
      if (which == 1) zpart[nf] += o[0] + o[1] + o[2] + o[3];
      if (which <= 1) {
        ushort* dst = (which == 0) ? qg : kg;
        const size_t rb = (bh * 2048 + tbase + mf * 16 + g4 * 4) * 64 + d;
#pragma unroll
        for (int j = 0; j < 4; ++j) dst[rb + (size_t)j * 64] = rnbf(o[j]);
      }
      if (which >= 1) {
        const int tb = (mf * 4 + g4) ^ ((d & 3) << 1);
        ushort4 pk;
        pk.x = rnbf(o[0]); pk.y = rnbf(o[1]); pk.z = rnbf(o[2]); pk.w = rnbf(o[3]);
        *(ushort4*)&wlds[d * 64 + tb * 4] = pk;
      }
    }
  }
  if (which == 1) {
    const int cc = tbase >> 7;
#pragma unroll
    for (int nf = 0; nf < 4; ++nf) {
      float zz = zpart[nf];
      zz += __shfl_xor(zz, 16);
      zz += __shfl_xor(zz, 32);
      if (l < 16) zp[((bh * NC_ + cc) * 2 + wm) * 64 + nf * 16 + l] = zz;
    }
  }
  if (which >= 1) {
    asm volatile("s_waitcnt lgkmcnt(0)" ::: "memory");
    __builtin_amdgcn_sched_barrier(0);
    ushort* tg = (which == 1) ? ktg : vtg;
#pragma unroll
    for (int it = 0; it < 8; ++it) {
      const int d = it * 8 + (l >> 3);
      const int t0 = (l & 7) * 8;
      const int blk = ((l & 7) * 2) ^ ((d & 3) << 1);
      bf16x8 vv_ = *(const bf16x8*)&wlds[d * 64 + blk * 4];
      *(bf16x8*)&tg[(bh * 64 + d) * 2048 + tbase + t0] = vv_;
    }
  }
}

// ---------------------------------------------------------------------------
// Kernel 5 (k_proj3): out = y @ w_proj^T. 128x128 tile, 256 threads
// (4 waves, 2x2 of 64x64), BK=32, 3-slab 48 KB LDS; grid 64x8 = 512.
// Same chunk-XOR swizzle / counted-vmcnt structure; 4 loads/stage -> VMW(4).
// ---------------------------------------------------------------------------
#define APB(sl_) ((sl_) * 4096)
#define BPB(sl_) (12288 + (sl_) * 4096)

#define STGP(sl_, tt_) { \
  gload_lds16(Asrc + (tt_) * 32,         &lds[APB(sl_) + tid * 8]); \
  gload_lds16(Asrc + (tt_) * 32 + 65536, &lds[APB(sl_) + 2048 + tid * 8]); \
  gload_lds16(Bsrc + (tt_) * 32,         &lds[BPB(sl_) + tid * 8]); \
  gload_lds16(Bsrc + (tt_) * 32 + 65536, &lds[BPB(sl_) + 2048 + tid * 8]); }

#define LDFRAGSP(sl_) \
  const ushort* pa = &lds[APB(sl_) + aOff]; \
  a0 = *(const bf16x8*)pa;          a1 = *(const bf16x8*)(pa + 512); \
  a2 = *(const bf16x8*)(pa + 1024); a3 = *(const bf16x8*)(pa + 1536); \
  const ushort* pb = &lds[BPB(sl_) + bOff]; \
  b0 = *(const bf16x8*)pb;          b1 = *(const bf16x8*)(pb + 512); \
  b2 = *(const bf16x8*)(pb + 1024); b3 = *(const bf16x8*)(pb + 1536);

__global__ __launch_bounds__(256, 2) void k_proj3(
    const ushort* __restrict__ yb, const ushort* __restrict__ wpb,
    float* __restrict__ out) {
  extern __shared__ ushort lds[];
  const int b = blockIdx.x;
  const int xcd = b & 7, idx = b >> 3;     // idx in [0,64)
  const int bm = xcd * 8 + (idx & 7);      // [0,64)
  const int bn = idx >> 3;                 // [0,8)
  const int tid = threadIdx.x;
  const int wv = tid >> 6, l = tid & 63;
  const int wm = wv >> 1, wn = wv & 1;
  const int c16 = l & 15, g4 = l >> 4;

  const ushort* Ag = yb + (size_t)bm * 128 * 1024;
  const ushort* Bg = wpb + (size_t)bn * 128 * 1024;
  const int gch = (tid & 3) ^ ((tid >> 3) & 3);
  const ushort* Asrc = Ag + (size_t)(tid >> 2) * 1024 + gch * 8;
  const ushort* Bsrc = Bg + (size_t)(tid >> 2) * 1024 + gch * 8;
  const int xq = (c16 >> 1) & 3;
  const int aOff = (wm * 64 + c16) * 32 + ((g4 ^ xq) << 3);
  const int bOff = (wn * 64 + c16) * 32 + ((g4 ^ xq) << 3);

  f32x4 acc[4][4] = {};

  STGP(0, 0);
  STGP(1, 1);
  int sl = 0;
#pragma unroll 3
  for (int t = 0; t < 30; ++t) {
    const int slN = sl ? sl - 1 : 2;  // (sl+2)%3
    VMW(4); BARR();
    bf16x8 a0, a1, a2, a3, b0, b1, b2, b3;
    LDFRAGSP(sl);
    STGP(slN, t + 2);
    MFMA16();
    sl = (sl == 2) ? 0 : sl + 1;
  }
  {  // t=30, slab 0
    VMW(4); BARR();
    bf16x8 a0, a1, a2, a3, b0, b1, b2, b3;
    LDFRAGSP(0);
    MFMA16();
  }
  {  // t=31, slab 1
    VMW(0); BARR();
    bf16x8 a0, a1, a2, a3, b0, b1, b2, b3;
    LDFRAGSP(1);
    MFMA16();
  }

  const int rowbase = bm * 128 + wm * 64 + g4 * 4;
  const int colbase = bn * 128 + wn * 64 + c16;
#pragma unroll
  for (int mf = 0; mf < 4; ++mf)
#pragma unroll
    for (int nf = 0; nf < 4; ++nf) {
      const size_t base = (size_t)(rowbase + mf * 16) * 1024 + colbase + nf * 16;
#pragma unroll
      for (int j = 0; j < 4; ++j)
        out[base + (size_t)j * 1024] = acc[mf][nf][j];
    }
}

// ---------------------------------------------------------------------------
// Kernel 2 (MFMA): per-chunk  ST[e][d] = sum_t v[t][e] k[t][d]  (fp32 out)
// ---------------------------------------------------------------------------
__global__ __launch_bounds__(256) void k_stats(const ushort* __restrict__ ktg,
                                               const ushort* __restrict__ vtg,
                                               float* __restrict__ Sc) {
  __shared__ __align__(16) ushort kT_s[64 * 128], vT_s[64 * 128];
  const int blk = blockIdx.x;
  const int bh = blk >> 4, c = blk & 15;
  const int tid = threadIdx.x;
  const int w = tid >> 6, l = tid & 63;
  const ushort* ktb = ktg + (size_t)bh * D_ * T_ + c * CHUNK_;
  const ushort* vtb = vtg + (size_t)bh * D_ * T_ + c * CHUNK_;
#pragma unroll
  for (int s2 = 0; s2 < 4; ++s2) {
    const int seg = w * 4 + s2;
    const int row = seg * 4 + (l >> 4);
    const int sb = ((l & 15) ^ (row & 7)) * 8;
    gload_lds16(ktb + (size_t)row * T_ + sb, &kT_s[seg * 512]);
    gload_lds16(vtb + (size_t)row * T_ + sb, &vT_s[seg * 512]);
  }
  __syncthreads();
  const int wr = w >> 1, wc = w & 1;
  f32x4 acc[2][2] = {};
#pragma unroll
  for (int kt = 0; kt < 4; ++kt) {
    const int g = kt * 32 + (l >> 4) * 8;
    bf16x8 av[2], bk[2];
#pragma unroll
    for (int rt = 0; rt < 2; ++rt) {
      const int e = wr * 32 + rt * 16 + (l & 15);
      av[rt] = *(const bf16x8*)&vT_s[e * 128 + (g ^ ((e & 7) << 3))];
    }
#pragma unroll
    for (int ct = 0; ct < 2; ++ct) {
      const int d = wc * 32 + ct * 16 + (l & 15);
      bk[ct] = *(const bf16x8*)&kT_s[d * 128 + (g ^ ((d & 7) << 3))];
    }
#pragma unroll
    for (int rt = 0; rt < 2; ++rt)
#pragma unroll
      for (int ct = 0; ct < 2; ++ct)
        acc[rt][ct] = __builtin_amdgcn_mfma_f32_16x16x32_bf16(av[rt], bk[ct],
                                                              acc[rt][ct], 0, 0, 0);
  }
  float* So = Sc + (size_t)blk * 4096;
#pragma unroll
  for (int rt = 0; rt < 2; ++rt)
#pragma unroll
    for (int ct = 0; ct < 2; ++ct)
#pragma unroll
      for (int jj = 0; jj < 4; ++jj)
        So[(wr * 32 + rt * 16 + (l >> 4) * 4 + jj) * 64 + wc * 32 + ct * 16 + (l & 15)] =
            acc[rt][ct][jj];
}

// ---------------------------------------------------------------------------
// Kernel 3: exclusive prefix over 16 chunks, parallelized.
// blocks 0..255: (bh, quarter) S-scan; blocks 256..319: z-scan per bh
// (z partials come in 2 halves per chunk from k_qkv2's wm split).
// ---------------------------------------------------------------------------
__global__ __launch_bounds__(256) void k_prefix2(const float* __restrict__ Sc,
                                                 ushort* __restrict__ STb,
                                                 const float* __restrict__ zp,
                                                 float* __restrict__ zout) {
  const int b = blockIdx.x;
  const int tid = threadIdx.x;
  if (b < 256) {
    const int bh = b >> 2, qt = b & 3;
    const float4* Sb = (const float4*)(Sc + (size_t)bh * NC_ * 4096) + qt * 256 + tid;
    ushort4* Ob = (ushort4*)(STb + (size_t)bh * NC_ * 4096) + qt * 256 + tid;
    float4 v[16];
#pragma unroll
    for (int c = 0; c < NC_; ++c) v[c] = Sb[c * 1024];
    float4 acc = make_float4(0.f, 0.f, 0.f, 0.f);
#pragma unroll
    for (int c = 0; c < NC_; ++c) {
      ushort4 o;
      o.x = rnbf(acc.x); o.y = rnbf(acc.y); o.z = rnbf(acc.z); o.w = rnbf(acc.w);
      Ob[c * 1024] = o;
      acc.x += v[c].x; acc.y += v[c].y; acc.z += v[c].z; acc.w += v[c].w;
    }
  } else {
    const int bh = b - 256;
    if (tid < 16) {
      const float4* zpb = (const float4*)(zp + (size_t)bh * NC_ * 128);
      float4* zob = (float4*)(zout + (size_t)bh * NC_ * 64);
      float4 t0[16], t1[16];
#pragma unroll
      for (int c = 0; c < NC_; ++c) {
        t0[c] = zpb[c * 32 + tid];
        t1[c] = zpb[c * 32 + 16 + tid];
      }
      float4 za = make_float4(0.f, 0.f, 0.f, 0.f);
#pragma unroll
      for (int c = 0; c < NC_; ++c) {
        zob[c * 16 + tid] = za;
        za.x += t0[c].x + t1[c].x; za.y += t0[c].y + t1[c].y;
        za.z += t0[c].z + t1[c].z; za.w += t0[c].w + t1[c].w;
      }
    }
  }
}

// ---------------------------------------------------------------------------
// Kernel 4 (MFMA): per-chunk output -> y bf16 [B,T,H,D].
// CAUSAL-AWARE (R12): wave w computes only key blocks jt <= w; even waves
// zero-fill the jt=w+1 strip; wave-local LDS fence instead of 2nd barrier.
// ---------------------------------------------------------------------------
__global__ __launch_bounds__(512, 4) void k_out(
    const ushort* __restrict__ qg, const ushort* __restrict__ kg,
    const ushort* __restrict__ vtg, const ushort* __restrict__ STb,
    const float* __restrict__ zg, ushort* __restrict__ yb) {
  __shared__ __align__(16) ushort k_s[128 * 64];
  __shared__ __align__(16) ushort vT_s[64 * 128];
  __shared__ __align__(16) ushort ST_s[64 * 64];
  __shared__ __align__(16) ushort P_s[128 * 128];
  __shared__ float z_s[64];
  __shared__ float dinter_s[128];
  const int blk = blockIdx.x;
  const int bh = blk >> 4, c = blk & 15;
  const int tid = threadIdx.x;
  const int w = tid >> 6, l = tid & 63;

  const ushort* kbase = kg + ((size_t)bh * T_ + c * CHUNK_) * D_;
  const ushort* vbase = vtg + (size_t)bh * D_ * T_ + c * CHUNK_;
  const ushort* sbase = STb + ((size_t)bh * NC_ + c) * 4096;
  {
    int seg = w, row = seg * 8 + (l >> 3);
    gload_lds16(kbase + (size_t)row * 64 + ((l & 7) ^ (row & 7)) * 8, &k_s[seg * 512]);
    seg = w + 8; row = seg * 8 + (l >> 3);
    gload_lds16(kbase + (size_t)row * 64 + ((l & 7) ^ (row & 7)) * 8, &k_s[seg * 512]);
  }
  {
    int seg = w, row = seg * 4 + (l >> 4);
    gload_lds16(vbase + (size_t)row * T_ + ((l & 15) ^ (row & 7)) * 8, &vT_s[seg * 512]);
    seg = w + 8; row = seg * 4 + (l >> 4);
    gload_lds16(vbase + (size_t)row * T_ + ((l & 15) ^ (row & 7)) * 8, &vT_s[seg * 512]);
  }
  {
    const int seg = w, row = seg * 8 + (l >> 3);
    gload_lds16(sbase + (size_t)row * 64 + ((l & 7) ^ (row & 7)) * 8, &ST_s[seg * 512]);
  }
  if (tid < 64) z_s[tid] = zg[((size_t)bh * NC_ + c) * 64 + tid];
  const int arow = w * 16 + (l & 15);
  const ushort* qrow = qg + ((size_t)bh * T_ + c * CHUNK_ + arow) * D_ + (l >> 4) * 8;
  bf16x8 qf0 = *(const bf16x8*)(qrow);
  bf16x8 qf1 = *(const bf16x8*)(qrow + 32);
  __syncthreads();

  // ---- causal QK^T: wave w only needs key blocks jt <= w ----
  const int crow0 = w * 16 + (l >> 4) * 4;
  float rsum[4] = {0.f, 0.f, 0.f, 0.f};
  for (int jt = 0; jt <= w; ++jt) {
    const int j = jt * 16 + (l & 15);
    const int sw = (j & 7) << 3, g = (l >> 4) * 8;
    bf16x8 b0 = *(const bf16x8*)&k_s[j * 64 + (g ^ sw)];
    bf16x8 b1 = *(const bf16x8*)&k_s[j * 64 + ((g + 32) ^ sw)];
    f32x4 s4 = {0.f, 0.f, 0.f, 0.f};
    s4 = __builtin_amdgcn_mfma_f32_16x16x32_bf16(qf0, b0, s4, 0, 0, 0);
    s4 = __builtin_amdgcn_mfma_f32_16x16x32_bf16(qf1, b1, s4, 0, 0, 0);
#pragma unroll
    for (int jj = 0; jj < 4; ++jj) {
      const int i = crow0 + jj;
      float s = (j <= i) ? s4[jj] : 0.f;
      rsum[jj] += s;
      P_s[i * 128 + (j ^ ((i & 7) << 3))] = rnbf(s);
    }
  }
  if (!(w & 1)) {  // even wave: zero-fill jt=w+1 so PV's boundary 32-block is defined
    const int j = (w + 1) * 16 + (l & 15);
#pragma unroll
    for (int jj = 0; jj < 4; ++jj) {
      const int i = crow0 + jj;
      P_s[i * 128 + (j ^ ((i & 7) << 3))] = 0;
    }
  }
  float di = 0.f;
#pragma unroll
  for (int jj = 0; jj < 8; ++jj) {
    di = fmaf(bf2f(qf0[jj]), z_s[(l >> 4) * 8 + jj], di);
    di = fmaf(bf2f(qf1[jj]), z_s[32 + (l >> 4) * 8 + jj], di);
  }
  di += __shfl_xor(di, 16);
  di += __shfl_xor(di, 32);
  if (l < 16) dinter_s[w * 16 + l] = di;
#pragma unroll
  for (int jj = 0; jj < 4; ++jj) {
    float r = rsum[jj];
    r += __shfl_xor(r, 1); r += __shfl_xor(r, 2);
    r += __shfl_xor(r, 4); r += __shfl_xor(r, 8);
    rsum[jj] = r;
  }
  // P_s / dinter_s rows are wave-local: wave-level LDS fence suffices.
  LGK0();

  f32x4 acc2[4] = {};
#pragma unroll
  for (int et = 0; et < 4; ++et) {
    const int e = et * 16 + (l & 15);
    const int sw = (e & 7) << 3, g = (l >> 4) * 8;
    bf16x8 s0 = *(const bf16x8*)&ST_s[e * 64 + (g ^ sw)];
    bf16x8 s1 = *(const bf16x8*)&ST_s[e * 64 + ((g + 32) ^ sw)];
    acc2[et] = __builtin_amdgcn_mfma_f32_16x16x32_bf16(qf0, s0, acc2[et], 0, 0, 0);
    acc2[et] = __builtin_amdgcn_mfma_f32_16x16x32_bf16(qf1, s1, acc2[et], 0, 0, 0);
  }
  const int prow = w * 16 + (l & 15);
  const int psw = (prow & 7) << 3;
  for (int jkt = 0; jkt <= (w >> 1); ++jkt) {
    bf16x8 pa = *(const bf16x8*)&P_s[prow * 128 + ((jkt * 32 + (l >> 4) * 8) ^ psw)];
#pragma unroll
    for (int et = 0; et < 4; ++et) {
      const int e = et * 16 + (l & 15);
      bf16x8 bv = *(const bf16x8*)&vT_s[e * 128 +
                                        ((jkt * 32 + (l >> 4) * 8) ^ ((e & 7) << 3))];
      acc2[et] = __builtin_amdgcn_mfma_f32_16x16x32_bf16(pa, bv, acc2[et], 0, 0, 0);
    }
  }
  float inv[4];
#pragma unroll
  for (int jj = 0; jj < 4; ++jj)
    inv[jj] = 1.0f / (rsum[jj] + dinter_s[crow0 + jj] + 1e-6f);
  const int b = bh >> 4, h = bh & 15;
#pragma unroll
  for (int et = 0; et < 4; ++et) {
    const int d = et * 16 + (l & 15);
#pragma unroll
    for (int jj = 0; jj < 4; ++jj) {
      const int t = c * CHUNK_ + crow0 + jj;
      yb[((size_t)(b * T_ + t) * H_ + h) * D_ + d] = rnbf(acc2[et][jj] * inv[jj]);
    }
  }
}

// ---------------------------------------------------------------------------
extern "C" void kernel_launch(void* const* d_in, const int* in_sizes, int n_in,
                              void* d_out, int out_size, void* d_ws, size_t ws_size,
                              hipStream_t stream) {
  const float* x = (const float*)d_in[0];
  const float* w_attn = (const float*)d_in[1];
  const float* w_proj = (const float*)d_in[2];
  float* out = (float*)d_out;

  ushort* xb = (ushort*)d_ws;                        // [8192,1024]
  ushort* wab = xb + (size_t)M_ * E_;                // [3072,1024]
  ushort* wpb = wab + (size_t)3 * E_ * E_;           // [1024,1024]
  ushort* qb = wpb + (size_t)E_ * E_;                // [bh][t][d]
  ushort* kbm = qb + (size_t)M_ * E_;                // [bh][t][d]
  ushort* kT = kbm + (size_t)M_ * E_;                // [bh][d][t]
  ushort* vT = kT + (size_t)M_ * E_;                 // [bh][d][t]
  ushort* yb = vT + (size_t)M_ * E_;                 // [B,T,H,D]
  ushort* STb = yb + (size_t)M_ * E_;                // [bh][c][e][d] bf16
  float* Schunk = (float*)(STb + (size_t)BH_ * NC_ * 4096);  // fp32
  float* zpart = Schunk + (size_t)BH_ * NC_ * 4096;  // [bh][c][2][64]
  float* zout = zpart + (size_t)BH_ * NC_ * 2 * 64;  // [bh][c][64]

  k_cvt3<<<2048, 256, 0, stream>>>(x, w_attn, w_proj, xb, wab, wpb);

  hipFuncSetAttribute((const void*)k_qkv2,
                      hipFuncAttributeMaxDynamicSharedMemorySize, 73728);
  hipFuncSetAttribute((const void*)k_proj3,
                      hipFuncAttributeMaxDynamicSharedMemorySize, 49152);

  k_qkv2<<<768, 512, 73728, stream>>>(xb, wab, qb, kbm, kT, vT, zpart);
  k_stats<<<1024, 256, 0, stream>>>(kT, vT, Schunk);
  k_prefix2<<<320, 256, 0, stream>>>(Schunk, STb, zpart, zout);
  k_out<<<1024, 512, 0, stream>>>(qb, kbm, vT, STb, zout, yb);
  k_proj3<<<512, 256, 49152, stream>>>(yb, wpb, out);
}